// Round 8
// baseline (464.848 us; speedup 1.0000x reference)
//
#include <hip/hip_runtime.h>
#include <hip/hip_bf16.h>
#include <cstdint>
#include <cstddef>

// Problem constants (from reference)
#define NSRC   200000
#define NF     128
#define NHID   1500
#define NHIDP  1536     // padded hidden dim (multiple of 128)
#define NCLS   64
#define E0N    1600000
#define E1N    500000
#define RES0   50000
#define RES1   10000

// CSR bucket-sort parameters
#define CH     4096                       // edges per chunk
#define NCH0   ((E0N + CH - 1) / CH)      // 391
#define NCH1   ((E1N + CH - 1) / CH)      // 123
#define NB0    ((RES0 + 255) / 256)      // 196 buckets of 256 targets
#define NB1    ((RES1 + 255) / 256)      // 40

#define PREP_BLOCKS  ((256 * NHIDP + 128 * NHIDP + NHIDP + 255) / 256)   // 2310
#define COPYX_BLOCKS ((NSRC * NF) / (256 * 8))                           // 12500

typedef __bf16 bf16x8 __attribute__((ext_vector_type(8)));
typedef float  f32x4  __attribute__((ext_vector_type(4)));
typedef unsigned short u16x8 __attribute__((ext_vector_type(8)));
typedef unsigned int u32;
typedef unsigned long long u64;

__device__ __forceinline__ unsigned short f2bf(float f) {
    union { float f; unsigned u; } v; v.f = f;
    unsigned r = v.u + 0x7fffu + ((v.u >> 16) & 1u);   // RNE
    return (unsigned short)(r >> 16);
}

// async 16B global -> LDS DMA (dest = wave-uniform lds base + lane*16)
__device__ __forceinline__ void lds_dma16(const void* g, void* lds) {
    __builtin_amdgcn_global_load_lds(
        (const __attribute__((address_space(1))) unsigned int*)g,
        (__attribute__((address_space(3))) unsigned int*)lds, 16, 0, 0);
}

// ---------------- setup: weight prep + x->bf16 copy (merged) -----------------
__global__ __launch_bounds__(256) void setup_kernel(
        const float* __restrict__ x, unsigned short* __restrict__ xbf,
        const float* __restrict__ W1r, const float* __restrict__ W1n,
        const float* __restrict__ b1,
        const float* __restrict__ W2r, const float* __restrict__ W2n,
        unsigned short* __restrict__ WcatT, unsigned short* __restrict__ W2catT,
        float* __restrict__ b1e) {
    int bid = blockIdx.x;
    if (bid < PREP_BLOCKS) {
        int id = bid * 256 + threadIdx.x;
        if (id < 256 * NHIDP) {
            int n = id >> 8, k = id & 255;
            float v = 0.f;
            if (n < NHID) v = (k < NF) ? W1r[k * NHID + n] : W1n[(k - NF) * NHID + n];
            WcatT[n * 256 + k] = f2bf(v);
        } else {
            int id2 = id - 256 * NHIDP;
            if (id2 < 128 * NHIDP) {
                int n = id2 / NHIDP, k = id2 % NHIDP;
                float v = 0.f;
                if (k < NHID) v = (n < 64) ? W2n[k * 64 + n] : W2r[k * 64 + (n - 64)];
                W2catT[n * NHIDP + k] = f2bf(v);
            } else {
                int c = id2 - 128 * NHIDP;
                if (c < NHIDP) b1e[c] = (c < NHID) ? b1[c] : 0.f;
            }
        }
    } else {
        size_t i = ((size_t)(bid - PREP_BLOCKS) * 256 + threadIdx.x) * 8;
        const float4* s = (const float4*)(x + i);
        float4 a = s[0], b = s[1];
        u16x8 o;
        o[0] = f2bf(a.x); o[1] = f2bf(a.y); o[2] = f2bf(a.z); o[3] = f2bf(a.w);
        o[4] = f2bf(b.x); o[5] = f2bf(b.y); o[6] = f2bf(b.z); o[7] = f2bf(b.w);
        *(u16x8*)(xbf + i) = o;
    }
}

// ---------------- CSR phase 1a: per-chunk bucket histogram (both graphs) -----
__device__ __forceinline__ void p1a_body(const int* __restrict__ tgt, int n,
                                         int nb, u32* __restrict__ H, int c) {
    __shared__ u32 lhist[256];
    int tid = threadIdx.x;
    lhist[tid] = 0;
    __syncthreads();
#pragma unroll
    for (int it = 0; it < CH / 256; ++it) {
        int i = c * CH + it * 256 + tid;
        if (i < n) atomicAdd(&lhist[((u32)tgt[i]) >> 8], 1u);
    }
    __syncthreads();
    if (tid < nb) H[c * nb + tid] = lhist[tid];
}

__global__ __launch_bounds__(256) void p1a_both_kernel(
        const int* __restrict__ t0, const int* __restrict__ t1,
        u32* __restrict__ H1, u32* __restrict__ H2) {
    int b = blockIdx.x;
    if (b < NCH0) p1a_body(t0, E0N, NB0, H1, b);
    else          p1a_body(t1, E1N, NB1, H2, b - NCH0);
}

// ---------------- bscan: per-bucket exclusive scan over chunks + totals ------
__device__ __forceinline__ void bscan_body(const u32* __restrict__ H,
                                           int nch, int nb, int b,
                                           u32* __restrict__ base_rel,
                                           u32* __restrict__ Bsum) {
    __shared__ u32 part[512];
    int t = threadIdx.x;
    part[t] = (t < nch) ? H[t * nb + b] : 0u;
    __syncthreads();
    for (int d = 1; d < 512; d <<= 1) {
        u32 v = part[t];
        u32 add = (t >= d) ? part[t - d] : 0u;
        __syncthreads();
        part[t] = v + add;
        __syncthreads();
    }
    if (t < nch) base_rel[t * nb + b] = (t == 0) ? 0u : part[t - 1];
    if (t == 0) Bsum[b] = part[nch - 1];
}

__global__ __launch_bounds__(512) void bscan_both_kernel(
        const u32* __restrict__ H1, u32* __restrict__ base1, u32* __restrict__ Bsum1,
        const u32* __restrict__ H2, u32* __restrict__ base2, u32* __restrict__ Bsum2) {
    int b = blockIdx.x;
    if (b < NB0) bscan_body(H1, NCH0, NB0, b, base1, Bsum1);
    else         bscan_body(H2, NCH1, NB1, b - NB0, base2, Bsum2);
}

// ---------------- boff: exclusive scan over bucket totals (both graphs) ------
__global__ __launch_bounds__(256) void boff_kernel(const u32* __restrict__ Bsum1,
                                                   u32* __restrict__ boff1, int nb1,
                                                   const u32* __restrict__ Bsum2,
                                                   u32* __restrict__ boff2, int nb2) {
    const u32* B = blockIdx.x ? Bsum2 : Bsum1;
    u32* O = blockIdx.x ? boff2 : boff1;
    int nb = blockIdx.x ? nb2 : nb1;
    __shared__ u32 part[256];
    int t = threadIdx.x;
    part[t] = (t < nb) ? B[t] : 0u;
    __syncthreads();
    for (int d = 1; d < 256; d <<= 1) {
        u32 v = part[t];
        u32 add = (t >= d) ? part[t - d] : 0u;
        __syncthreads();
        part[t] = v + add;
        __syncthreads();
    }
    if (t < nb) O[t] = (t == 0) ? 0u : part[t - 1];
}

// ---------------- phase 1b: bucket-grouped scatter of (tgt,src) pairs --------
__device__ __forceinline__ void p1b_body(const int* __restrict__ src,
                                         const int* __restrict__ tgt, int n,
                                         int nb, const u32* __restrict__ base_rel,
                                         const u32* __restrict__ boff,
                                         u64* __restrict__ bucketed, int c) {
    __shared__ u32 lcur[256];
    __shared__ u32 lbase[256];
    int tid = threadIdx.x;
    lcur[tid] = 0;
    if (tid < nb) lbase[tid] = base_rel[c * nb + tid] + boff[tid];
    __syncthreads();
#pragma unroll
    for (int it = 0; it < CH / 256; ++it) {
        int i = c * CH + it * 256 + tid;
        if (i < n) {
            u32 t = (u32)tgt[i];
            u32 s = (u32)src[i];
            u32 b = t >> 8;
            u32 r = atomicAdd(&lcur[b], 1u);
            bucketed[lbase[b] + r] = ((u64)t << 32) | (u64)s;
        }
    }
}

__global__ __launch_bounds__(256) void p1b_both_kernel(
        const int* __restrict__ s0, const int* __restrict__ t0,
        const u32* __restrict__ base1, const u32* __restrict__ boff1,
        u64* __restrict__ bkt1,
        const int* __restrict__ s1, const int* __restrict__ t1,
        const u32* __restrict__ base2, const u32* __restrict__ boff2,
        u64* __restrict__ bkt2) {
    int b = blockIdx.x;
    if (b < NCH0) p1b_body(s0, t0, E0N, NB0, base1, boff1, bkt1, b);
    else          p1b_body(s1, t1, E1N, NB1, base2, boff2, bkt2, b - NCH0);
}

// ---------------- phase 2: per-bucket sort -> CSR + per-target off/cnt -------
__device__ __forceinline__ void p2_body(const u64* __restrict__ bucketed,
                                        const u32* __restrict__ boff,
                                        int nb, int res, int etot,
                                        int* __restrict__ csr,
                                        u32* __restrict__ off_out,
                                        u32* __restrict__ cnt_out, int b) {
    __shared__ u32 lhist[256];
    __shared__ u32 part[256];
    __shared__ u32 cur[256];
    int tid = threadIdx.x;
    u32 start = boff[b];
    u32 end = (b == nb - 1) ? (u32)etot : boff[b + 1];
    u32 count = end - start;
    if (tid < 256) lhist[tid] = 0;
    __syncthreads();
    for (u32 i = tid; i < count; i += 1024) {
        u32 t = (u32)(bucketed[start + i] >> 32);
        atomicAdd(&lhist[t & 255u], 1u);
    }
    __syncthreads();
    if (tid < 256) part[tid] = lhist[tid];
    __syncthreads();
    for (int d = 1; d < 256; d <<= 1) {
        u32 v = (tid < 256) ? part[tid] : 0u;
        u32 add = (tid >= d && tid < 256) ? part[tid - d] : 0u;
        __syncthreads();
        if (tid < 256) part[tid] = v + add;
        __syncthreads();
    }
    if (tid < 256) {
        u32 excl = (tid == 0) ? 0u : part[tid - 1];
        cur[tid] = excl;
        int tg = (b << 8) + tid;
        if (tg < res) {
            off_out[tg] = start + excl;
            cnt_out[tg] = lhist[tid];
        }
    }
    __syncthreads();
    for (u32 i = tid; i < count; i += 1024) {
        u64 pr = bucketed[start + i];
        u32 lt = ((u32)(pr >> 32)) & 255u;
        u32 r = atomicAdd(&cur[lt], 1u);
        csr[start + r] = (int)(u32)pr;
    }
}

__global__ __launch_bounds__(1024) void p2_both_kernel(
        const u64* __restrict__ bkt1, const u32* __restrict__ boff1,
        int* __restrict__ csr1, u32* __restrict__ off1, u32* __restrict__ cnt1,
        const u64* __restrict__ bkt2, const u32* __restrict__ boff2,
        int* __restrict__ csr2, u32* __restrict__ off2, u32* __restrict__ cnt2) {
    int b = blockIdx.x;
    if (b < NB0) p2_body(bkt1, boff1, NB0, RES0, E0N, csr1, off1, cnt1, b);
    else         p2_body(bkt2, boff2, NB1, RES1, E1N, csr2, off2, cnt2, b - NB0);
}

// ---------------- layer-1 mean aggregation: 1 wave/row, u32 gathers ----------
__global__ __launch_bounds__(256) void agg1_csr_kernel(
        const u32* __restrict__ xb32, const int* __restrict__ csr,
        const u32* __restrict__ off, const u32* __restrict__ cnt,
        u32* __restrict__ mean1_32) {
    int row = blockIdx.x * 4 + (threadIdx.x >> 6);
    int lane = threadIdx.x & 63;
    if (row >= RES0) return;
    u32 base = off[row], deg = cnt[row];
    float x0 = 0.f, y0 = 0.f, x1 = 0.f, y1 = 0.f;
    float x2 = 0.f, y2 = 0.f, x3 = 0.f, y3 = 0.f;
    u32 e = 0;
    for (; e + 4 <= deg; e += 4) {
        int s0 = csr[base + e], s1 = csr[base + e + 1];
        int s2 = csr[base + e + 2], s3 = csr[base + e + 3];
        u32 w0 = xb32[(size_t)s0 * 64 + lane];
        u32 w1 = xb32[(size_t)s1 * 64 + lane];
        u32 w2 = xb32[(size_t)s2 * 64 + lane];
        u32 w3 = xb32[(size_t)s3 * 64 + lane];
        union { u32 u; float f; } a, b;
        a.u = w0 << 16; b.u = w0 & 0xffff0000u; x0 += a.f; y0 += b.f;
        a.u = w1 << 16; b.u = w1 & 0xffff0000u; x1 += a.f; y1 += b.f;
        a.u = w2 << 16; b.u = w2 & 0xffff0000u; x2 += a.f; y2 += b.f;
        a.u = w3 << 16; b.u = w3 & 0xffff0000u; x3 += a.f; y3 += b.f;
    }
    for (; e < deg; ++e) {
        u32 w = xb32[(size_t)csr[base + e] * 64 + lane];
        union { u32 u; float f; } a, b;
        a.u = w << 16; b.u = w & 0xffff0000u; x0 += a.f; y0 += b.f;
    }
    float inv = 1.0f / fmaxf((float)deg, 1.0f);
    float mx = ((x0 + x1) + (x2 + x3)) * inv;
    float my = ((y0 + y1) + (y2 + y3)) * inv;
    mean1_32[(size_t)row * 64 + lane] = (u32)f2bf(mx) | ((u32)f2bf(my) << 16);
}

// ---------------- fused GEMM staging helper ----------------------------------
__device__ __forceinline__ void stage_chunk(
        const unsigned short* __restrict__ xbf, const unsigned short* __restrict__ mean1,
        const unsigned short* __restrict__ WcatT, int m0, int j, int kt,
        unsigned short* As, unsigned short* Bs, int wid, int lane) {
    int ksel = kt * 32;
    const unsigned short* srcA = (ksel < 128)
        ? xbf + (size_t)m0 * NF + ksel
        : mean1 + (size_t)m0 * NF + (ksel - 128);
#pragma unroll
    for (int ci = 0; ci < 2; ++ci) {
        int cb = ci * 256 + wid * 64;
        int chunk = cb + lane;
        int n = chunk >> 2, kc = chunk & 3;
        lds_dma16(srcA + (size_t)n * NF + kc * 8, &As[cb * 8]);
    }
    const unsigned short* srcB = WcatT + (size_t)(j * 128) * 256 + ksel;
#pragma unroll
    for (int ci = 0; ci < 2; ++ci) {
        int cb = ci * 256 + wid * 64;
        int chunk = cb + lane;
        int n = chunk >> 2, kc = chunk & 3;
        lds_dma16(srcB + (size_t)n * 256 + kc * 8, &Bs[cb * 8]);
    }
}

// ---------------- fused GEMM: ping-pong pipeline + transposed accumulators ---
// mfma(b, a, acc) => acc holds the TRANSPOSED tile: lane&15 -> row m,
// regs -> 4 consecutive cols. Epilogue: ds_write_b64; p-write: dwordx4.
__global__ __launch_bounds__(256, 2) void fused_gemm_kernel(
        const unsigned short* __restrict__ xbf, const unsigned short* __restrict__ mean1,
        const unsigned short* __restrict__ WcatT, const float* __restrict__ b1e,
        const unsigned short* __restrict__ W2catT,
        float* __restrict__ pp0, float* __restrict__ pp1) {
    __shared__ __align__(16) unsigned short As[2][128 * 32];
    __shared__ __align__(16) unsigned short Bs[2][128 * 32];
    __shared__ __align__(16) unsigned short Ht[128 * 136];

    int m0 = blockIdx.x * 128;
    int jb = blockIdx.y * 6;
    float* pout = blockIdx.y ? pp1 : pp0;
    int tid = threadIdx.x;
    int lane = tid & 63, wid = tid >> 6;
    int wm = wid >> 1, wn = wid & 1;
    int quad = lane >> 4, l15 = lane & 15;

    f32x4 pacc[4][4] = {};

    // prologue: first chunk of first j
    stage_chunk(xbf, mean1, WcatT, m0, jb, 0, As[0], Bs[0], wid, lane);

    for (int j = jb; j < jb + 6; ++j) {
        f32x4 hacc[4][4] = {};
#pragma unroll
        for (int kt = 0; kt < 8; ++kt) {
            __syncthreads();                     // buf[kt&1] ready; prior reads done
            if (kt < 7)
                stage_chunk(xbf, mean1, WcatT, m0, j, kt + 1,
                            As[(kt + 1) & 1], Bs[(kt + 1) & 1], wid, lane);
            const unsigned short* Asb = As[kt & 1];
            const unsigned short* Bsb = Bs[kt & 1];
            bf16x8 a[4], b[4];
#pragma unroll
            for (int mi = 0; mi < 4; ++mi)
                a[mi] = *(const bf16x8*)(&Asb[(wm * 64 + mi * 16 + l15) * 32 + quad * 8]);
#pragma unroll
            for (int ni = 0; ni < 4; ++ni)
                b[ni] = *(const bf16x8*)(&Bsb[(wn * 64 + ni * 16 + l15) * 32 + quad * 8]);
#pragma unroll
            for (int mi = 0; mi < 4; ++mi)
#pragma unroll
                for (int ni = 0; ni < 4; ++ni)
                    hacc[mi][ni] = __builtin_amdgcn_mfma_f32_16x16x32_bf16(b[ni], a[mi], hacc[mi][ni], 0, 0, 0);
        }
        // epilogue 1: h^T tiles -> bias+relu -> bf16 -> Ht[m][k], b64 stores
#pragma unroll
        for (int ni = 0; ni < 4; ++ni) {
            int n0 = wn * 64 + ni * 16 + quad * 4;          // local hidden col base
            float4 bv = *(const float4*)(b1e + j * 128 + n0);
#pragma unroll
            for (int mi = 0; mi < 4; ++mi) {
                int m = wm * 64 + mi * 16 + l15;
                ushort4 o;
                o.x = f2bf(fmaxf(hacc[mi][ni][0] + bv.x, 0.f));
                o.y = f2bf(fmaxf(hacc[mi][ni][1] + bv.y, 0.f));
                o.z = f2bf(fmaxf(hacc[mi][ni][2] + bv.z, 0.f));
                o.w = f2bf(fmaxf(hacc[mi][ni][3] + bv.w, 0.f));
                *(ushort4*)(&Ht[m * 136 + n0]) = o;
            }
        }
        __syncthreads();                         // Ht visible; As/Bs free
        if (j + 1 < jb + 6)                      // prefetch next j during stage 2
            stage_chunk(xbf, mean1, WcatT, m0, j + 1, 0, As[0], Bs[0], wid, lane);
        // stage 2: pacc^T += (Ht @ W2cat_j)^T
#pragma unroll
        for (int kk2 = 0; kk2 < 128; kk2 += 32) {
            bf16x8 a2[4], b2[4];
#pragma unroll
            for (int mi = 0; mi < 4; ++mi)
                a2[mi] = *(const bf16x8*)(&Ht[(wm * 64 + mi * 16 + l15) * 136 + kk2 + quad * 8]);
#pragma unroll
            for (int ni = 0; ni < 4; ++ni)
                b2[ni] = *(const bf16x8*)(W2catT + (size_t)(wn * 64 + ni * 16 + l15) * NHIDP
                                          + j * 128 + kk2 + quad * 8);
#pragma unroll
            for (int mi = 0; mi < 4; ++mi)
#pragma unroll
                for (int ni = 0; ni < 4; ++ni)
                    pacc[mi][ni] = __builtin_amdgcn_mfma_f32_16x16x32_bf16(b2[ni], a2[mi], pacc[mi][ni], 0, 0, 0);
        }
        // no barrier: next j's kt=0 sync covers Ht/As/Bs reuse ordering
    }

    // write p^T tiles: per lane 4 consecutive cols -> dwordx4
#pragma unroll
    for (int mi = 0; mi < 4; ++mi) {
        int gr = m0 + wm * 64 + mi * 16 + l15;
        if (gr < RES0) {
#pragma unroll
            for (int ni = 0; ni < 4; ++ni) {
                int gc0 = wn * 64 + ni * 16 + quad * 4;
                *(float4*)(&pout[(size_t)gr * 128 + gc0]) = *(float4*)(&pacc[mi][ni]);
            }
        }
    }
}

// ---------------- padd: pp0 += pp1 ------------------------------------------
__global__ __launch_bounds__(256) void padd_kernel(float* __restrict__ pp0,
                                                   const float* __restrict__ pp1) {
    size_t i = (size_t)blockIdx.x * 256 + threadIdx.x;
    f32x4 a = ((const f32x4*)pp0)[i];
    f32x4 b = ((const f32x4*)pp1)[i];
    ((f32x4*)pp0)[i] = a + b;
}

// ---------------- fused layer-2 aggregation + log_softmax --------------------
__global__ __launch_bounds__(64) void final_csr_kernel(
        const float* __restrict__ p, const int* __restrict__ csr,
        const u32* __restrict__ off, const u32* __restrict__ cnt,
        const float* __restrict__ b2, float* __restrict__ out) {
    int row = blockIdx.x;
    int c = threadIdx.x;
    u32 base = off[row], deg = cnt[row];
    float a0 = 0.f, a1 = 0.f, a2 = 0.f, a3 = 0.f;
    u32 e = 0;
    for (; e + 4 <= deg; e += 4) {
        int s0 = csr[base + e], s1 = csr[base + e + 1];
        int s2 = csr[base + e + 2], s3 = csr[base + e + 3];
        a0 += p[(size_t)s0 * 128 + c];
        a1 += p[(size_t)s1 * 128 + c];
        a2 += p[(size_t)s2 * 128 + c];
        a3 += p[(size_t)s3 * 128 + c];
    }
    for (; e < deg; ++e) a0 += p[(size_t)csr[base + e] * 128 + c];
    float mean = ((a0 + a1) + (a2 + a3)) / fmaxf((float)deg, 1.0f);
    float v = p[(size_t)row * 128 + 64 + c] + mean + b2[c];
    float m = v;
#pragma unroll
    for (int o = 32; o > 0; o >>= 1) m = fmaxf(m, __shfl_xor(m, o, 64));
    float ex = expf(v - m);
    float s = ex;
#pragma unroll
    for (int o = 32; o > 0; o >>= 1) s += __shfl_xor(s, o, 64);
    out[(size_t)row * 64 + c] = v - m - logf(s);
}

extern "C" void kernel_launch(void* const* d_in, const int* in_sizes, int n_in,
                              void* d_out, int out_size, void* d_ws, size_t ws_size,
                              hipStream_t stream) {
    const float* x   = (const float*)d_in[0];
    const float* W1r = (const float*)d_in[1];
    const float* W1n = (const float*)d_in[2];
    const float* b1  = (const float*)d_in[3];
    const float* W2r = (const float*)d_in[4];
    const float* W2n = (const float*)d_in[5];
    const float* b2  = (const float*)d_in[6];
    const int* es0 = (const int*)d_in[7];
    const int* et0 = (const int*)d_in[8];
    const int* es1 = (const int*)d_in[9];
    const int* et1 = (const int*)d_in[10];
    float* out = (float*)d_out;

    char* ws = (char*)d_ws;
    // --- region 0 [0, 25.6 MB): pp1 aliases CSR-phase temporaries (all dead
    //     before fused_gemm writes pp1) ---
    const size_t PPBYTES = (size_t)RES0 * 128 * 4;   // 25,600,000
    float* pp1 = (float*)ws;
    size_t o0 = 0;
    auto alloc0 = [&](size_t bytes) {
        void* ptr = ws + o0;
        o0 = (o0 + bytes + 255) & ~(size_t)255;
        return ptr;
    };
    u64* bkt1  = (u64*)alloc0((size_t)E0N * 8);        // 12.8 MB
    u64* bkt2  = (u64*)alloc0((size_t)E1N * 8);        //  4.0 MB
    int* csr1  = (int*)alloc0((size_t)E0N * 4);        //  6.4 MB
    u32* H1    = (u32*)alloc0((size_t)NCH0 * NB0 * 4);
    u32* base1 = (u32*)alloc0((size_t)NCH0 * NB0 * 4);
    u32* H2    = (u32*)alloc0((size_t)NCH1 * NB1 * 4);
    u32* base2 = (u32*)alloc0((size_t)NCH1 * NB1 * 4);
    u32* Bsum1 = (u32*)alloc0((size_t)NB0 * 4);
    u32* Bsum2 = (u32*)alloc0((size_t)NB1 * 4);
    u32* boff1 = (u32*)alloc0((size_t)NB0 * 4);
    u32* boff2 = (u32*)alloc0((size_t)NB1 * 4);
    u32* off1  = (u32*)alloc0((size_t)RES0 * 4);
    u32* cnt1  = (u32*)alloc0((size_t)RES0 * 4);
    // (o0 ≈ 24.3 MB < 25.6 MB — fits under pp1)

    // --- live region, starts after pp1 ---
    size_t off_ = PPBYTES;
    auto alloc = [&](size_t bytes) {
        void* ptr = ws + off_;
        off_ = (off_ + bytes + 255) & ~(size_t)255;
        return ptr;
    };
    int* csr2  = (int*)alloc((size_t)E1N * 4);
    u32* off2  = (u32*)alloc((size_t)RES1 * 4);
    u32* cnt2  = (u32*)alloc((size_t)RES1 * 4);
    unsigned short* xbf    = (unsigned short*)alloc((size_t)NSRC * NF * 2);
    unsigned short* mean1  = (unsigned short*)alloc((size_t)(RES0 + 128) * NF * 2);
    unsigned short* WcatT  = (unsigned short*)alloc((size_t)NHIDP * 256 * 2);
    unsigned short* W2catT = (unsigned short*)alloc((size_t)128 * NHIDP * 2);
    float*          b1e    = (float*)alloc((size_t)NHIDP * 4);
    float*          pp0    = (float*)alloc(PPBYTES);

    setup_kernel<<<PREP_BLOCKS + COPYX_BLOCKS, 256, 0, stream>>>(
        x, xbf, W1r, W1n, b1, W2r, W2n, WcatT, W2catT, b1e);

    p1a_both_kernel<<<NCH0 + NCH1, 256, 0, stream>>>(et0, et1, H1, H2);
    bscan_both_kernel<<<NB0 + NB1, 512, 0, stream>>>(H1, base1, Bsum1, H2, base2, Bsum2);
    boff_kernel<<<2, 256, 0, stream>>>(Bsum1, boff1, NB0, Bsum2, boff2, NB1);
    p1b_both_kernel<<<NCH0 + NCH1, 256, 0, stream>>>(
        es0, et0, base1, boff1, bkt1, es1, et1, base2, boff2, bkt2);
    p2_both_kernel<<<NB0 + NB1, 1024, 0, stream>>>(
        bkt1, boff1, csr1, off1, cnt1, bkt2, boff2, csr2, off2, cnt2);

    agg1_csr_kernel<<<(RES0 + 3) / 4, 256, 0, stream>>>(
        (const u32*)xbf, csr1, off1, cnt1, (u32*)mean1);

    fused_gemm_kernel<<<dim3((RES0 + 127) / 128, 2), 256, 0, stream>>>(
        xbf, mean1, WcatT, b1e, W2catT, pp0, pp1);

    padd_kernel<<<(RES0 * 128 / 4 + 255) / 256, 256, 0, stream>>>(pp0, pp1);

    final_csr_kernel<<<RES1, 64, 0, stream>>>(pp0, csr2, off2, cnt2, b2, out);
}

// Round 9
// 460.264 us; speedup vs baseline: 1.0100x; 1.0100x over previous
//
#include <hip/hip_runtime.h>
#include <hip/hip_bf16.h>
#include <cstdint>
#include <cstddef>

// Problem constants (from reference)
#define NSRC   200000
#define NF     128
#define NHID   1500
#define NHIDP  1536     // padded hidden dim (multiple of 128)
#define NCLS   64
#define E0N    1600000
#define E1N    500000
#define RES0   50000
#define RES1   10000

// CSR bucket-sort parameters
#define CH     4096                       // edges per chunk
#define NCH0   ((E0N + CH - 1) / CH)      // 391
#define NCH1   ((E1N + CH - 1) / CH)      // 123
#define NB0    ((RES0 + 255) / 256)      // 196 buckets of 256 targets
#define NB1    ((RES1 + 255) / 256)      // 40

#define PREP_BLOCKS  ((256 * NHIDP + 128 * NHIDP + NHIDP + 255) / 256)   // 2310
#define COPYX_BLOCKS ((NSRC * NF) / (256 * 8))                           // 12500

typedef __bf16 bf16x8 __attribute__((ext_vector_type(8)));
typedef float  f32x4  __attribute__((ext_vector_type(4)));
typedef unsigned short u16x8 __attribute__((ext_vector_type(8)));
typedef unsigned int u32;
typedef unsigned long long u64;

__device__ __forceinline__ unsigned short f2bf(float f) {
    union { float f; unsigned u; } v; v.f = f;
    unsigned r = v.u + 0x7fffu + ((v.u >> 16) & 1u);   // RNE
    return (unsigned short)(r >> 16);
}

// async 16B global -> LDS DMA (dest = wave-uniform lds base + lane*16)
__device__ __forceinline__ void lds_dma16(const void* g, void* lds) {
    __builtin_amdgcn_global_load_lds(
        (const __attribute__((address_space(1))) unsigned int*)g,
        (__attribute__((address_space(3))) unsigned int*)lds, 16, 0, 0);
}

// raw barrier/wait primitives: s_barrier WITHOUT the compiler's vmcnt(0) drain.
__device__ __forceinline__ void raw_barrier() {
    __asm__ volatile("s_barrier" ::: "memory");
}
__device__ __forceinline__ void wait_vm4() {
    __asm__ volatile("s_waitcnt vmcnt(4)" ::: "memory");
}
__device__ __forceinline__ void wait_vm0() {
    __asm__ volatile("s_waitcnt vmcnt(0)" ::: "memory");
}
__device__ __forceinline__ void wait_lgkm0() {
    __asm__ volatile("s_waitcnt lgkmcnt(0)" ::: "memory");
}

// ---------------- setup: weight prep + x->bf16 copy (merged) -----------------
__global__ __launch_bounds__(256) void setup_kernel(
        const float* __restrict__ x, unsigned short* __restrict__ xbf,
        const float* __restrict__ W1r, const float* __restrict__ W1n,
        const float* __restrict__ b1,
        const float* __restrict__ W2r, const float* __restrict__ W2n,
        unsigned short* __restrict__ WcatT, unsigned short* __restrict__ W2catT,
        float* __restrict__ b1e) {
    int bid = blockIdx.x;
    if (bid < PREP_BLOCKS) {
        int id = bid * 256 + threadIdx.x;
        if (id < 256 * NHIDP) {
            int n = id >> 8, k = id & 255;
            float v = 0.f;
            if (n < NHID) v = (k < NF) ? W1r[k * NHID + n] : W1n[(k - NF) * NHID + n];
            WcatT[n * 256 + k] = f2bf(v);
        } else {
            int id2 = id - 256 * NHIDP;
            if (id2 < 128 * NHIDP) {
                int n = id2 / NHIDP, k = id2 % NHIDP;
                float v = 0.f;
                if (k < NHID) v = (n < 64) ? W2n[k * 64 + n] : W2r[k * 64 + (n - 64)];
                W2catT[n * NHIDP + k] = f2bf(v);
            } else {
                int c = id2 - 128 * NHIDP;
                if (c < NHIDP) b1e[c] = (c < NHID) ? b1[c] : 0.f;
            }
        }
    } else {
        size_t i = ((size_t)(bid - PREP_BLOCKS) * 256 + threadIdx.x) * 8;
        const float4* s = (const float4*)(x + i);
        float4 a = s[0], b = s[1];
        u16x8 o;
        o[0] = f2bf(a.x); o[1] = f2bf(a.y); o[2] = f2bf(a.z); o[3] = f2bf(a.w);
        o[4] = f2bf(b.x); o[5] = f2bf(b.y); o[6] = f2bf(b.z); o[7] = f2bf(b.w);
        *(u16x8*)(xbf + i) = o;
    }
}

// ---------------- CSR phase 1a: per-chunk bucket histogram (both graphs) -----
__device__ __forceinline__ void p1a_body(const int* __restrict__ tgt, int n,
                                         int nb, u32* __restrict__ H, int c) {
    __shared__ u32 lhist[256];
    int tid = threadIdx.x;
    lhist[tid] = 0;
    __syncthreads();
#pragma unroll
    for (int it = 0; it < CH / 256; ++it) {
        int i = c * CH + it * 256 + tid;
        if (i < n) atomicAdd(&lhist[((u32)tgt[i]) >> 8], 1u);
    }
    __syncthreads();
    if (tid < nb) H[c * nb + tid] = lhist[tid];
}

__global__ __launch_bounds__(256) void p1a_both_kernel(
        const int* __restrict__ t0, const int* __restrict__ t1,
        u32* __restrict__ H1, u32* __restrict__ H2) {
    int b = blockIdx.x;
    if (b < NCH0) p1a_body(t0, E0N, NB0, H1, b);
    else          p1a_body(t1, E1N, NB1, H2, b - NCH0);
}

// ---------------- bscan: per-bucket exclusive scan over chunks + totals ------
__device__ __forceinline__ void bscan_body(const u32* __restrict__ H,
                                           int nch, int nb, int b,
                                           u32* __restrict__ base_rel,
                                           u32* __restrict__ Bsum) {
    __shared__ u32 part[512];
    int t = threadIdx.x;
    part[t] = (t < nch) ? H[t * nb + b] : 0u;
    __syncthreads();
    for (int d = 1; d < 512; d <<= 1) {
        u32 v = part[t];
        u32 add = (t >= d) ? part[t - d] : 0u;
        __syncthreads();
        part[t] = v + add;
        __syncthreads();
    }
    if (t < nch) base_rel[t * nb + b] = (t == 0) ? 0u : part[t - 1];
    if (t == 0) Bsum[b] = part[nch - 1];
}

__global__ __launch_bounds__(512) void bscan_both_kernel(
        const u32* __restrict__ H1, u32* __restrict__ base1, u32* __restrict__ Bsum1,
        const u32* __restrict__ H2, u32* __restrict__ base2, u32* __restrict__ Bsum2) {
    int b = blockIdx.x;
    if (b < NB0) bscan_body(H1, NCH0, NB0, b, base1, Bsum1);
    else         bscan_body(H2, NCH1, NB1, b - NB0, base2, Bsum2);
}

// ---------------- boff: exclusive scan over bucket totals (both graphs) ------
__global__ __launch_bounds__(256) void boff_kernel(const u32* __restrict__ Bsum1,
                                                   u32* __restrict__ boff1, int nb1,
                                                   const u32* __restrict__ Bsum2,
                                                   u32* __restrict__ boff2, int nb2) {
    const u32* B = blockIdx.x ? Bsum2 : Bsum1;
    u32* O = blockIdx.x ? boff2 : boff1;
    int nb = blockIdx.x ? nb2 : nb1;
    __shared__ u32 part[256];
    int t = threadIdx.x;
    part[t] = (t < nb) ? B[t] : 0u;
    __syncthreads();
    for (int d = 1; d < 256; d <<= 1) {
        u32 v = part[t];
        u32 add = (t >= d) ? part[t - d] : 0u;
        __syncthreads();
        part[t] = v + add;
        __syncthreads();
    }
    if (t < nb) O[t] = (t == 0) ? 0u : part[t - 1];
}

// ---------------- phase 1b: bucket-grouped scatter of (tgt,src) pairs --------
__device__ __forceinline__ void p1b_body(const int* __restrict__ src,
                                         const int* __restrict__ tgt, int n,
                                         int nb, const u32* __restrict__ base_rel,
                                         const u32* __restrict__ boff,
                                         u64* __restrict__ bucketed, int c) {
    __shared__ u32 lcur[256];
    __shared__ u32 lbase[256];
    int tid = threadIdx.x;
    lcur[tid] = 0;
    if (tid < nb) lbase[tid] = base_rel[c * nb + tid] + boff[tid];
    __syncthreads();
#pragma unroll
    for (int it = 0; it < CH / 256; ++it) {
        int i = c * CH + it * 256 + tid;
        if (i < n) {
            u32 t = (u32)tgt[i];
            u32 s = (u32)src[i];
            u32 b = t >> 8;
            u32 r = atomicAdd(&lcur[b], 1u);
            bucketed[lbase[b] + r] = ((u64)t << 32) | (u64)s;
        }
    }
}

__global__ __launch_bounds__(256) void p1b_both_kernel(
        const int* __restrict__ s0, const int* __restrict__ t0,
        const u32* __restrict__ base1, const u32* __restrict__ boff1,
        u64* __restrict__ bkt1,
        const int* __restrict__ s1, const int* __restrict__ t1,
        const u32* __restrict__ base2, const u32* __restrict__ boff2,
        u64* __restrict__ bkt2) {
    int b = blockIdx.x;
    if (b < NCH0) p1b_body(s0, t0, E0N, NB0, base1, boff1, bkt1, b);
    else          p1b_body(s1, t1, E1N, NB1, base2, boff2, bkt2, b - NCH0);
}

// ---------------- phase 2: per-bucket sort -> CSR + per-target off/cnt -------
__device__ __forceinline__ void p2_body(const u64* __restrict__ bucketed,
                                        const u32* __restrict__ boff,
                                        int nb, int res, int etot,
                                        int* __restrict__ csr,
                                        u32* __restrict__ off_out,
                                        u32* __restrict__ cnt_out, int b) {
    __shared__ u32 lhist[256];
    __shared__ u32 part[256];
    __shared__ u32 cur[256];
    int tid = threadIdx.x;
    u32 start = boff[b];
    u32 end = (b == nb - 1) ? (u32)etot : boff[b + 1];
    u32 count = end - start;
    if (tid < 256) lhist[tid] = 0;
    __syncthreads();
    for (u32 i = tid; i < count; i += 1024) {
        u32 t = (u32)(bucketed[start + i] >> 32);
        atomicAdd(&lhist[t & 255u], 1u);
    }
    __syncthreads();
    if (tid < 256) part[tid] = lhist[tid];
    __syncthreads();
    for (int d = 1; d < 256; d <<= 1) {
        u32 v = (tid < 256) ? part[tid] : 0u;
        u32 add = (tid >= d && tid < 256) ? part[tid - d] : 0u;
        __syncthreads();
        if (tid < 256) part[tid] = v + add;
        __syncthreads();
    }
    if (tid < 256) {
        u32 excl = (tid == 0) ? 0u : part[tid - 1];
        cur[tid] = excl;
        int tg = (b << 8) + tid;
        if (tg < res) {
            off_out[tg] = start + excl;
            cnt_out[tg] = lhist[tid];
        }
    }
    __syncthreads();
    for (u32 i = tid; i < count; i += 1024) {
        u64 pr = bucketed[start + i];
        u32 lt = ((u32)(pr >> 32)) & 255u;
        u32 r = atomicAdd(&cur[lt], 1u);
        csr[start + r] = (int)(u32)pr;
    }
}

__global__ __launch_bounds__(1024) void p2_both_kernel(
        const u64* __restrict__ bkt1, const u32* __restrict__ boff1,
        int* __restrict__ csr1, u32* __restrict__ off1, u32* __restrict__ cnt1,
        const u64* __restrict__ bkt2, const u32* __restrict__ boff2,
        int* __restrict__ csr2, u32* __restrict__ off2, u32* __restrict__ cnt2) {
    int b = blockIdx.x;
    if (b < NB0) p2_body(bkt1, boff1, NB0, RES0, E0N, csr1, off1, cnt1, b);
    else         p2_body(bkt2, boff2, NB1, RES1, E1N, csr2, off2, cnt2, b - NB0);
}

// ---------------- layer-1 mean aggregation: 1 wave/row, u32 gathers ----------
__global__ __launch_bounds__(256) void agg1_csr_kernel(
        const u32* __restrict__ xb32, const int* __restrict__ csr,
        const u32* __restrict__ off, const u32* __restrict__ cnt,
        u32* __restrict__ mean1_32) {
    int row = blockIdx.x * 4 + (threadIdx.x >> 6);
    int lane = threadIdx.x & 63;
    if (row >= RES0) return;
    u32 base = off[row], deg = cnt[row];
    float x0 = 0.f, y0 = 0.f, x1 = 0.f, y1 = 0.f;
    float x2 = 0.f, y2 = 0.f, x3 = 0.f, y3 = 0.f;
    u32 e = 0;
    for (; e + 4 <= deg; e += 4) {
        int s0 = csr[base + e], s1 = csr[base + e + 1];
        int s2 = csr[base + e + 2], s3 = csr[base + e + 3];
        u32 w0 = xb32[(size_t)s0 * 64 + lane];
        u32 w1 = xb32[(size_t)s1 * 64 + lane];
        u32 w2 = xb32[(size_t)s2 * 64 + lane];
        u32 w3 = xb32[(size_t)s3 * 64 + lane];
        union { u32 u; float f; } a, b;
        a.u = w0 << 16; b.u = w0 & 0xffff0000u; x0 += a.f; y0 += b.f;
        a.u = w1 << 16; b.u = w1 & 0xffff0000u; x1 += a.f; y1 += b.f;
        a.u = w2 << 16; b.u = w2 & 0xffff0000u; x2 += a.f; y2 += b.f;
        a.u = w3 << 16; b.u = w3 & 0xffff0000u; x3 += a.f; y3 += b.f;
    }
    for (; e < deg; ++e) {
        u32 w = xb32[(size_t)csr[base + e] * 64 + lane];
        union { u32 u; float f; } a, b;
        a.u = w << 16; b.u = w & 0xffff0000u; x0 += a.f; y0 += b.f;
    }
    float inv = 1.0f / fmaxf((float)deg, 1.0f);
    float mx = ((x0 + x1) + (x2 + x3)) * inv;
    float my = ((y0 + y1) + (y2 + y3)) * inv;
    mean1_32[(size_t)row * 64 + lane] = (u32)f2bf(mx) | ((u32)f2bf(my) << 16);
}

// ---------------- fused GEMM staging helper ----------------------------------
__device__ __forceinline__ void stage_chunk(
        const unsigned short* __restrict__ xbf, const unsigned short* __restrict__ mean1,
        const unsigned short* __restrict__ WcatT, int m0, int j, int kt,
        unsigned short* As, unsigned short* Bs, int wid, int lane) {
    int ksel = kt * 32;
    const unsigned short* srcA = (ksel < 128)
        ? xbf + (size_t)m0 * NF + ksel
        : mean1 + (size_t)m0 * NF + (ksel - 128);
#pragma unroll
    for (int ci = 0; ci < 2; ++ci) {
        int cb = ci * 256 + wid * 64;
        int chunk = cb + lane;
        int n = chunk >> 2, kc = chunk & 3;
        lds_dma16(srcA + (size_t)n * NF + kc * 8, &As[cb * 8]);
    }
    const unsigned short* srcB = WcatT + (size_t)(j * 128) * 256 + ksel;
#pragma unroll
    for (int ci = 0; ci < 2; ++ci) {
        int cb = ci * 256 + wid * 64;
        int chunk = cb + lane;
        int n = chunk >> 2, kc = chunk & 3;
        lds_dma16(srcB + (size_t)n * 256 + kc * 8, &Bs[cb * 8]);
    }
}

// ---------------- fused GEMM: depth-2 prefetch w/ raw barriers ---------------
// Key change vs R8: __syncthreads (vmcnt(0) drain) replaced by
// s_waitcnt vmcnt(4) + raw s_barrier over a 3-deep circular As/Bs buffer.
// Chunk g's DMA issued 2 iterations (~700 cyc) before use -> latency hidden.
// LDS: 3*(8+8) KB + Ht 32 KB (XOR-swizzled, no pad) = 80 KB -> 2 blocks/CU.
__global__ __launch_bounds__(256, 2) void fused_gemm_kernel(
        const unsigned short* __restrict__ xbf, const unsigned short* __restrict__ mean1,
        const unsigned short* __restrict__ WcatT, const float* __restrict__ b1e,
        const unsigned short* __restrict__ W2catT,
        float* __restrict__ pp0, float* __restrict__ pp1) {
    __shared__ __align__(16) unsigned short As[3][128 * 32];
    __shared__ __align__(16) unsigned short Bs[3][128 * 32];
    __shared__ __align__(16) unsigned short Ht[128 * 128];   // XOR-swizzled

    int m0 = blockIdx.x * 128;
    int jb = blockIdx.y * 6;
    float* pout = blockIdx.y ? pp1 : pp0;
    int tid = threadIdx.x;
    int lane = tid & 63, wid = tid >> 6;
    int wm = wid >> 1, wn = wid & 1;
    int quad = lane >> 4, l15 = lane & 15;

    f32x4 pacc[4][4] = {};

    // prologue: chunks g=0,1 into buffers 0,1
    stage_chunk(xbf, mean1, WcatT, m0, jb, 0, As[0], Bs[0], wid, lane);
    stage_chunk(xbf, mean1, WcatT, m0, jb, 1, As[1], Bs[1], wid, lane);

#pragma unroll
    for (int jj = 0; jj < 6; ++jj) {
        int j = jb + jj;
        f32x4 hacc[4][4] = {};
#pragma unroll
        for (int kt = 0; kt < 8; ++kt) {
            const int g = jj * 8 + kt;
            // ensure chunk g landed; leave g+1's 4 DMAs in flight
            if (g == 47) wait_vm0(); else wait_vm4();
            raw_barrier();
            // prefetch chunk g+2 (may cross into next j)
            if (g + 2 < 48) {
                int g2 = g + 2;
                stage_chunk(xbf, mean1, WcatT, m0, jb + (g2 >> 3), g2 & 7,
                            As[g2 % 3], Bs[g2 % 3], wid, lane);
            }
            const unsigned short* Asb = As[g % 3];
            const unsigned short* Bsb = Bs[g % 3];
            bf16x8 a[4], b[4];
#pragma unroll
            for (int mi = 0; mi < 4; ++mi)
                a[mi] = *(const bf16x8*)(&Asb[(wm * 64 + mi * 16 + l15) * 32 + quad * 8]);
#pragma unroll
            for (int ni = 0; ni < 4; ++ni)
                b[ni] = *(const bf16x8*)(&Bsb[(wn * 64 + ni * 16 + l15) * 32 + quad * 8]);
#pragma unroll
            for (int mi = 0; mi < 4; ++mi)
#pragma unroll
                for (int ni = 0; ni < 4; ++ni)
                    hacc[mi][ni] = __builtin_amdgcn_mfma_f32_16x16x32_bf16(b[ni], a[mi], hacc[mi][ni], 0, 0, 0);
        }
        // epilogue 1: bias+relu -> bf16 -> Ht (XOR-swizzled [m][g'*8]) b64 stores
#pragma unroll
        for (int ni = 0; ni < 4; ++ni) {
            int n0 = wn * 64 + ni * 16 + quad * 4;
            float4 bv = *(const float4*)(b1e + j * 128 + n0);
#pragma unroll
            for (int mi = 0; mi < 4; ++mi) {
                int m = wm * 64 + mi * 16 + l15;
                int gsw = ((n0 >> 3) ^ (m & 15));
                ushort4 o;
                o.x = f2bf(fmaxf(hacc[mi][ni][0] + bv.x, 0.f));
                o.y = f2bf(fmaxf(hacc[mi][ni][1] + bv.y, 0.f));
                o.z = f2bf(fmaxf(hacc[mi][ni][2] + bv.z, 0.f));
                o.w = f2bf(fmaxf(hacc[mi][ni][3] + bv.w, 0.f));
                *(ushort4*)(&Ht[m * 128 + gsw * 8 + (n0 & 7)]) = o;
            }
        }
        wait_lgkm0();       // Ht writes visible
        raw_barrier();      // no vmcnt drain: j+1 prefetches keep flying
        // stage 2: pacc^T += (Ht @ W2cat_j)^T, Ht read via swizzle
#pragma unroll
        for (int kk2 = 0; kk2 < 128; kk2 += 32) {
            bf16x8 a2[4], b2[4];
#pragma unroll
            for (int mi = 0; mi < 4; ++mi) {
                int m = wm * 64 + mi * 16 + l15;
                int gr = (kk2 >> 3) + quad;
                int gsw = gr ^ (m & 15);
                a2[mi] = *(const bf16x8*)(&Ht[m * 128 + gsw * 8]);
            }
#pragma unroll
            for (int ni = 0; ni < 4; ++ni)
                b2[ni] = *(const bf16x8*)(W2catT + (size_t)(wn * 64 + ni * 16 + l15) * NHIDP
                                          + j * 128 + kk2 + quad * 8);
#pragma unroll
            for (int mi = 0; mi < 4; ++mi)
#pragma unroll
                for (int ni = 0; ni < 4; ++ni)
                    pacc[mi][ni] = __builtin_amdgcn_mfma_f32_16x16x32_bf16(b2[ni], a2[mi], pacc[mi][ni], 0, 0, 0);
        }
        // no barrier here: next jj's kt=0 barrier orders Ht reuse
    }

    // write p^T tiles: per lane 4 consecutive cols -> dwordx4
#pragma unroll
    for (int mi = 0; mi < 4; ++mi) {
        int gr = m0 + wm * 64 + mi * 16 + l15;
        if (gr < RES0) {
#pragma unroll
            for (int ni = 0; ni < 4; ++ni) {
                int gc0 = wn * 64 + ni * 16 + quad * 4;
                *(float4*)(&pout[(size_t)gr * 128 + gc0]) = *(float4*)(&pacc[mi][ni]);
            }
        }
    }
}

// ---------------- padd: pp0 += pp1 ------------------------------------------
__global__ __launch_bounds__(256) void padd_kernel(float* __restrict__ pp0,
                                                   const float* __restrict__ pp1) {
    size_t i = (size_t)blockIdx.x * 256 + threadIdx.x;
    f32x4 a = ((const f32x4*)pp0)[i];
    f32x4 b = ((const f32x4*)pp1)[i];
    ((f32x4*)pp0)[i] = a + b;
}

// ---------------- fused layer-2 aggregation + log_softmax --------------------
__global__ __launch_bounds__(64) void final_csr_kernel(
        const float* __restrict__ p, const int* __restrict__ csr,
        const u32* __restrict__ off, const u32* __restrict__ cnt,
        const float* __restrict__ b2, float* __restrict__ out) {
    int row = blockIdx.x;
    int c = threadIdx.x;
    u32 base = off[row], deg = cnt[row];
    float a0 = 0.f, a1 = 0.f, a2 = 0.f, a3 = 0.f;
    u32 e = 0;
    for (; e + 4 <= deg; e += 4) {
        int s0 = csr[base + e], s1 = csr[base + e + 1];
        int s2 = csr[base + e + 2], s3 = csr[base + e + 3];
        a0 += p[(size_t)s0 * 128 + c];
        a1 += p[(size_t)s1 * 128 + c];
        a2 += p[(size_t)s2 * 128 + c];
        a3 += p[(size_t)s3 * 128 + c];
    }
    for (; e < deg; ++e) a0 += p[(size_t)csr[base + e] * 128 + c];
    float mean = ((a0 + a1) + (a2 + a3)) / fmaxf((float)deg, 1.0f);
    float v = p[(size_t)row * 128 + 64 + c] + mean + b2[c];
    float m = v;
#pragma unroll
    for (int o = 32; o > 0; o >>= 1) m = fmaxf(m, __shfl_xor(m, o, 64));
    float ex = expf(v - m);
    float s = ex;
#pragma unroll
    for (int o = 32; o > 0; o >>= 1) s += __shfl_xor(s, o, 64);
    out[(size_t)row * 64 + c] = v - m - logf(s);
}

extern "C" void kernel_launch(void* const* d_in, const int* in_sizes, int n_in,
                              void* d_out, int out_size, void* d_ws, size_t ws_size,
                              hipStream_t stream) {
    const float* x   = (const float*)d_in[0];
    const float* W1r = (const float*)d_in[1];
    const float* W1n = (const float*)d_in[2];
    const float* b1  = (const float*)d_in[3];
    const float* W2r = (const float*)d_in[4];
    const float* W2n = (const float*)d_in[5];
    const float* b2  = (const float*)d_in[6];
    const int* es0 = (const int*)d_in[7];
    const int* et0 = (const int*)d_in[8];
    const int* es1 = (const int*)d_in[9];
    const int* et1 = (const int*)d_in[10];
    float* out = (float*)d_out;

    char* ws = (char*)d_ws;
    // --- region 0 [0, 25.6 MB): pp1 aliases CSR-phase temporaries (all dead
    //     before fused_gemm writes pp1) ---
    const size_t PPBYTES = (size_t)RES0 * 128 * 4;   // 25,600,000
    float* pp1 = (float*)ws;
    size_t o0 = 0;
    auto alloc0 = [&](size_t bytes) {
        void* ptr = ws + o0;
        o0 = (o0 + bytes + 255) & ~(size_t)255;
        return ptr;
    };
    u64* bkt1  = (u64*)alloc0((size_t)E0N * 8);        // 12.8 MB
    u64* bkt2  = (u64*)alloc0((size_t)E1N * 8);        //  4.0 MB
    int* csr1  = (int*)alloc0((size_t)E0N * 4);        //  6.4 MB
    u32* H1    = (u32*)alloc0((size_t)NCH0 * NB0 * 4);
    u32* base1 = (u32*)alloc0((size_t)NCH0 * NB0 * 4);
    u32* H2    = (u32*)alloc0((size_t)NCH1 * NB1 * 4);
    u32* base2 = (u32*)alloc0((size_t)NCH1 * NB1 * 4);
    u32* Bsum1 = (u32*)alloc0((size_t)NB0 * 4);
    u32* Bsum2 = (u32*)alloc0((size_t)NB1 * 4);
    u32* boff1 = (u32*)alloc0((size_t)NB0 * 4);
    u32* boff2 = (u32*)alloc0((size_t)NB1 * 4);
    u32* off1  = (u32*)alloc0((size_t)RES0 * 4);
    u32* cnt1  = (u32*)alloc0((size_t)RES0 * 4);
    // (o0 ≈ 24.3 MB < 25.6 MB — fits under pp1)

    // --- live region, starts after pp1 ---
    size_t off_ = PPBYTES;
    auto alloc = [&](size_t bytes) {
        void* ptr = ws + off_;
        off_ = (off_ + bytes + 255) & ~(size_t)255;
        return ptr;
    };
    int* csr2  = (int*)alloc((size_t)E1N * 4);
    u32* off2  = (u32*)alloc((size_t)RES1 * 4);
    u32* cnt2  = (u32*)alloc((size_t)RES1 * 4);
    unsigned short* xbf    = (unsigned short*)alloc((size_t)NSRC * NF * 2);
    unsigned short* mean1  = (unsigned short*)alloc((size_t)(RES0 + 128) * NF * 2);
    unsigned short* WcatT  = (unsigned short*)alloc((size_t)NHIDP * 256 * 2);
    unsigned short* W2catT = (unsigned short*)alloc((size_t)128 * NHIDP * 2);
    float*          b1e    = (float*)alloc((size_t)NHIDP * 4);
    float*          pp0    = (float*)alloc(PPBYTES);

    setup_kernel<<<PREP_BLOCKS + COPYX_BLOCKS, 256, 0, stream>>>(
        x, xbf, W1r, W1n, b1, W2r, W2n, WcatT, W2catT, b1e);

    p1a_both_kernel<<<NCH0 + NCH1, 256, 0, stream>>>(et0, et1, H1, H2);
    bscan_both_kernel<<<NB0 + NB1, 512, 0, stream>>>(H1, base1, Bsum1, H2, base2, Bsum2);
    boff_kernel<<<2, 256, 0, stream>>>(Bsum1, boff1, NB0, Bsum2, boff2, NB1);
    p1b_both_kernel<<<NCH0 + NCH1, 256, 0, stream>>>(
        es0, et0, base1, boff1, bkt1, es1, et1, base2, boff2, bkt2);
    p2_both_kernel<<<NB0 + NB1, 1024, 0, stream>>>(
        bkt1, boff1, csr1, off1, cnt1, bkt2, boff2, csr2, off2, cnt2);

    agg1_csr_kernel<<<(RES0 + 3) / 4, 256, 0, stream>>>(
        (const u32*)xbf, csr1, off1, cnt1, (u32*)mean1);

    fused_gemm_kernel<<<dim3((RES0 + 127) / 128, 2), 256, 0, stream>>>(
        xbf, mean1, WcatT, b1e, W2catT, pp0, pp1);

    padd_kernel<<<(RES0 * 128 / 4 + 255) / 256, 256, 0, stream>>>(pp0, pp1);

    final_csr_kernel<<<RES1, 64, 0, stream>>>(pp0, csr2, off2, cnt2, b2, out);
}

// Round 10
// 445.066 us; speedup vs baseline: 1.0444x; 1.0341x over previous
//
#include <hip/hip_runtime.h>
#include <hip/hip_bf16.h>
#include <cstdint>
#include <cstddef>

// Problem constants (from reference)
#define NSRC   200000
#define NF     128
#define NHID   1500
#define NHIDP  1536     // padded hidden dim (multiple of 128)
#define NCLS   64
#define E0N    1600000
#define E1N    500000
#define RES0   50000
#define RES1   10000

// CSR bucket-sort parameters
#define CH     4096                       // edges per chunk
#define NCH0   ((E0N + CH - 1) / CH)      // 391
#define NCH1   ((E1N + CH - 1) / CH)      // 123
#define NB0    ((RES0 + 255) / 256)      // 196 buckets of 256 targets
#define NB1    ((RES1 + 255) / 256)      // 40

#define PREP_BLOCKS  ((256 * NHIDP + 128 * NHIDP + NHIDP + 255) / 256)   // 2310
#define COPYX_BLOCKS ((NSRC * NF) / (256 * 8))                           // 12500

typedef __bf16 bf16x8 __attribute__((ext_vector_type(8)));
typedef float  f32x4  __attribute__((ext_vector_type(4)));
typedef unsigned short u16x8 __attribute__((ext_vector_type(8)));
typedef unsigned int u32;
typedef unsigned long long u64;

__device__ __forceinline__ unsigned short f2bf(float f) {
    union { float f; unsigned u; } v; v.f = f;
    unsigned r = v.u + 0x7fffu + ((v.u >> 16) & 1u);   // RNE
    return (unsigned short)(r >> 16);
}
__device__ __forceinline__ float bf2f(unsigned short b) {
    union { u32 u; float f; } v; v.u = ((u32)b) << 16;
    return v.f;
}

// async 16B global -> LDS DMA (dest = wave-uniform lds base + lane*16)
__device__ __forceinline__ void lds_dma16(const void* g, void* lds) {
    __builtin_amdgcn_global_load_lds(
        (const __attribute__((address_space(1))) unsigned int*)g,
        (__attribute__((address_space(3))) unsigned int*)lds, 16, 0, 0);
}

// raw barrier/wait primitives: s_barrier WITHOUT the compiler's vmcnt(0) drain.
__device__ __forceinline__ void raw_barrier() {
    __asm__ volatile("s_barrier" ::: "memory");
}
__device__ __forceinline__ void wait_vm4() {
    __asm__ volatile("s_waitcnt vmcnt(4)" ::: "memory");
}
__device__ __forceinline__ void wait_vm0() {
    __asm__ volatile("s_waitcnt vmcnt(0)" ::: "memory");
}
__device__ __forceinline__ void wait_lgkm0() {
    __asm__ volatile("s_waitcnt lgkmcnt(0)" ::: "memory");
}

// ---------------- setup: weight prep + x->bf16 copy (merged) -----------------
__global__ __launch_bounds__(256) void setup_kernel(
        const float* __restrict__ x, unsigned short* __restrict__ xbf,
        const float* __restrict__ W1r, const float* __restrict__ W1n,
        const float* __restrict__ b1,
        const float* __restrict__ W2r, const float* __restrict__ W2n,
        unsigned short* __restrict__ WcatT, unsigned short* __restrict__ W2catT,
        float* __restrict__ b1e) {
    int bid = blockIdx.x;
    if (bid < PREP_BLOCKS) {
        int id = bid * 256 + threadIdx.x;
        if (id < 256 * NHIDP) {
            int n = id >> 8, k = id & 255;
            float v = 0.f;
            if (n < NHID) v = (k < NF) ? W1r[k * NHID + n] : W1n[(k - NF) * NHID + n];
            WcatT[n * 256 + k] = f2bf(v);
        } else {
            int id2 = id - 256 * NHIDP;
            if (id2 < 128 * NHIDP) {
                int n = id2 / NHIDP, k = id2 % NHIDP;
                float v = 0.f;
                if (k < NHID) v = (n < 64) ? W2n[k * 64 + n] : W2r[k * 64 + (n - 64)];
                W2catT[n * NHIDP + k] = f2bf(v);
            } else {
                int c = id2 - 128 * NHIDP;
                if (c < NHIDP) b1e[c] = (c < NHID) ? b1[c] : 0.f;
            }
        }
    } else {
        size_t i = ((size_t)(bid - PREP_BLOCKS) * 256 + threadIdx.x) * 8;
        const float4* s = (const float4*)(x + i);
        float4 a = s[0], b = s[1];
        u16x8 o;
        o[0] = f2bf(a.x); o[1] = f2bf(a.y); o[2] = f2bf(a.z); o[3] = f2bf(a.w);
        o[4] = f2bf(b.x); o[5] = f2bf(b.y); o[6] = f2bf(b.z); o[7] = f2bf(b.w);
        *(u16x8*)(xbf + i) = o;
    }
}

// ---------------- CSR phase 1a: per-chunk bucket histogram (both graphs) -----
__device__ __forceinline__ void p1a_body(const int* __restrict__ tgt, int n,
                                         int nb, u32* __restrict__ H, int c) {
    __shared__ u32 lhist[256];
    int tid = threadIdx.x;
    lhist[tid] = 0;
    __syncthreads();
#pragma unroll
    for (int it = 0; it < CH / 256; ++it) {
        int i = c * CH + it * 256 + tid;
        if (i < n) atomicAdd(&lhist[((u32)tgt[i]) >> 8], 1u);
    }
    __syncthreads();
    if (tid < nb) H[c * nb + tid] = lhist[tid];
}

__global__ __launch_bounds__(256) void p1a_both_kernel(
        const int* __restrict__ t0, const int* __restrict__ t1,
        u32* __restrict__ H1, u32* __restrict__ H2) {
    int b = blockIdx.x;
    if (b < NCH0) p1a_body(t0, E0N, NB0, H1, b);
    else          p1a_body(t1, E1N, NB1, H2, b - NCH0);
}

// ---------------- bscan: per-bucket exclusive scan over chunks + totals ------
__device__ __forceinline__ void bscan_body(const u32* __restrict__ H,
                                           int nch, int nb, int b,
                                           u32* __restrict__ base_rel,
                                           u32* __restrict__ Bsum) {
    __shared__ u32 part[512];
    int t = threadIdx.x;
    part[t] = (t < nch) ? H[t * nb + b] : 0u;
    __syncthreads();
    for (int d = 1; d < 512; d <<= 1) {
        u32 v = part[t];
        u32 add = (t >= d) ? part[t - d] : 0u;
        __syncthreads();
        part[t] = v + add;
        __syncthreads();
    }
    if (t < nch) base_rel[t * nb + b] = (t == 0) ? 0u : part[t - 1];
    if (t == 0) Bsum[b] = part[nch - 1];
}

__global__ __launch_bounds__(512) void bscan_both_kernel(
        const u32* __restrict__ H1, u32* __restrict__ base1, u32* __restrict__ Bsum1,
        const u32* __restrict__ H2, u32* __restrict__ base2, u32* __restrict__ Bsum2) {
    int b = blockIdx.x;
    if (b < NB0) bscan_body(H1, NCH0, NB0, b, base1, Bsum1);
    else         bscan_body(H2, NCH1, NB1, b - NB0, base2, Bsum2);
}

// ---------------- boff: exclusive scan over bucket totals (both graphs) ------
__global__ __launch_bounds__(256) void boff_kernel(const u32* __restrict__ Bsum1,
                                                   u32* __restrict__ boff1, int nb1,
                                                   const u32* __restrict__ Bsum2,
                                                   u32* __restrict__ boff2, int nb2) {
    const u32* B = blockIdx.x ? Bsum2 : Bsum1;
    u32* O = blockIdx.x ? boff2 : boff1;
    int nb = blockIdx.x ? nb2 : nb1;
    __shared__ u32 part[256];
    int t = threadIdx.x;
    part[t] = (t < nb) ? B[t] : 0u;
    __syncthreads();
    for (int d = 1; d < 256; d <<= 1) {
        u32 v = part[t];
        u32 add = (t >= d) ? part[t - d] : 0u;
        __syncthreads();
        part[t] = v + add;
        __syncthreads();
    }
    if (t < nb) O[t] = (t == 0) ? 0u : part[t - 1];
}

// ---------------- phase 1b: bucket-grouped scatter of (tgt,src) pairs --------
__device__ __forceinline__ void p1b_body(const int* __restrict__ src,
                                         const int* __restrict__ tgt, int n,
                                         int nb, const u32* __restrict__ base_rel,
                                         const u32* __restrict__ boff,
                                         u64* __restrict__ bucketed, int c) {
    __shared__ u32 lcur[256];
    __shared__ u32 lbase[256];
    int tid = threadIdx.x;
    lcur[tid] = 0;
    if (tid < nb) lbase[tid] = base_rel[c * nb + tid] + boff[tid];
    __syncthreads();
#pragma unroll
    for (int it = 0; it < CH / 256; ++it) {
        int i = c * CH + it * 256 + tid;
        if (i < n) {
            u32 t = (u32)tgt[i];
            u32 s = (u32)src[i];
            u32 b = t >> 8;
            u32 r = atomicAdd(&lcur[b], 1u);
            bucketed[lbase[b] + r] = ((u64)t << 32) | (u64)s;
        }
    }
}

__global__ __launch_bounds__(256) void p1b_both_kernel(
        const int* __restrict__ s0, const int* __restrict__ t0,
        const u32* __restrict__ base1, const u32* __restrict__ boff1,
        u64* __restrict__ bkt1,
        const int* __restrict__ s1, const int* __restrict__ t1,
        const u32* __restrict__ base2, const u32* __restrict__ boff2,
        u64* __restrict__ bkt2) {
    int b = blockIdx.x;
    if (b < NCH0) p1b_body(s0, t0, E0N, NB0, base1, boff1, bkt1, b);
    else          p1b_body(s1, t1, E1N, NB1, base2, boff2, bkt2, b - NCH0);
}

// ---------------- phase 2: per-bucket sort -> CSR + per-target off/cnt -------
__device__ __forceinline__ void p2_body(const u64* __restrict__ bucketed,
                                        const u32* __restrict__ boff,
                                        int nb, int res, int etot,
                                        int* __restrict__ csr,
                                        u32* __restrict__ off_out,
                                        u32* __restrict__ cnt_out, int b) {
    __shared__ u32 lhist[256];
    __shared__ u32 part[256];
    __shared__ u32 cur[256];
    int tid = threadIdx.x;
    u32 start = boff[b];
    u32 end = (b == nb - 1) ? (u32)etot : boff[b + 1];
    u32 count = end - start;
    if (tid < 256) lhist[tid] = 0;
    __syncthreads();
    for (u32 i = tid; i < count; i += 1024) {
        u32 t = (u32)(bucketed[start + i] >> 32);
        atomicAdd(&lhist[t & 255u], 1u);
    }
    __syncthreads();
    if (tid < 256) part[tid] = lhist[tid];
    __syncthreads();
    for (int d = 1; d < 256; d <<= 1) {
        u32 v = (tid < 256) ? part[tid] : 0u;
        u32 add = (tid >= d && tid < 256) ? part[tid - d] : 0u;
        __syncthreads();
        if (tid < 256) part[tid] = v + add;
        __syncthreads();
    }
    if (tid < 256) {
        u32 excl = (tid == 0) ? 0u : part[tid - 1];
        cur[tid] = excl;
        int tg = (b << 8) + tid;
        if (tg < res) {
            off_out[tg] = start + excl;
            cnt_out[tg] = lhist[tid];
        }
    }
    __syncthreads();
    for (u32 i = tid; i < count; i += 1024) {
        u64 pr = bucketed[start + i];
        u32 lt = ((u32)(pr >> 32)) & 255u;
        u32 r = atomicAdd(&cur[lt], 1u);
        csr[start + r] = (int)(u32)pr;
    }
}

__global__ __launch_bounds__(1024) void p2_both_kernel(
        const u64* __restrict__ bkt1, const u32* __restrict__ boff1,
        int* __restrict__ csr1, u32* __restrict__ off1, u32* __restrict__ cnt1,
        const u64* __restrict__ bkt2, const u32* __restrict__ boff2,
        int* __restrict__ csr2, u32* __restrict__ off2, u32* __restrict__ cnt2) {
    int b = blockIdx.x;
    if (b < NB0) p2_body(bkt1, boff1, NB0, RES0, E0N, csr1, off1, cnt1, b);
    else         p2_body(bkt2, boff2, NB1, RES1, E1N, csr2, off2, cnt2, b - NB0);
}

// ---------------- layer-1 mean: 1 wave/row, 16 lanes/row, 4 edges/instr ------
__global__ __launch_bounds__(256) void agg1_csr_kernel(
        const unsigned short* __restrict__ xbf, const int* __restrict__ csr,
        const u32* __restrict__ off, const u32* __restrict__ cnt,
        unsigned short* __restrict__ mean1) {
    int row = blockIdx.x * 4 + (threadIdx.x >> 6);
    int lane = threadIdx.x & 63;
    if (row >= RES0) return;
    int q = lane >> 4, c16 = lane & 15;            // edge slot, 16B chunk
    u32 base = off[row], deg = cnt[row];
    float acc[8] = {};
    u32 e = 0;
    // 8 edges in flight (2 gathers/iter)
    for (; e + 8 <= deg; e += 8) {
        int s0 = csr[base + e + q];
        int s1 = csr[base + e + 4 + q];
        u16x8 v0 = *(const u16x8*)(xbf + (size_t)s0 * NF + c16 * 8);
        u16x8 v1 = *(const u16x8*)(xbf + (size_t)s1 * NF + c16 * 8);
#pragma unroll
        for (int i = 0; i < 8; ++i) acc[i] += bf2f(v0[i]) + bf2f(v1[i]);
    }
    for (; e + 4 <= deg; e += 4) {
        int s0 = csr[base + e + q];
        u16x8 v0 = *(const u16x8*)(xbf + (size_t)s0 * NF + c16 * 8);
#pragma unroll
        for (int i = 0; i < 8; ++i) acc[i] += bf2f(v0[i]);
    }
    if (e < deg) {
        bool valid = (e + q) < deg;
        int s0 = csr[base + (valid ? e + q : e)];
        u16x8 v0 = *(const u16x8*)(xbf + (size_t)s0 * NF + c16 * 8);
        if (valid) {
#pragma unroll
            for (int i = 0; i < 8; ++i) acc[i] += bf2f(v0[i]);
        }
    }
    // reduce across the 4 edge slots (lane bits 4,5)
#pragma unroll
    for (int i = 0; i < 8; ++i) {
        acc[i] += __shfl_xor(acc[i], 32, 64);
        acc[i] += __shfl_xor(acc[i], 16, 64);
    }
    if (q == 0) {
        float inv = 1.0f / fmaxf((float)deg, 1.0f);
        u16x8 o;
#pragma unroll
        for (int i = 0; i < 8; ++i) o[i] = f2bf(acc[i] * inv);
        *(u16x8*)(mean1 + (size_t)row * NF + c16 * 8) = o;
    }
}

// ---------------- fused GEMM staging helper ----------------------------------
__device__ __forceinline__ void stage_chunk(
        const unsigned short* __restrict__ xbf, const unsigned short* __restrict__ mean1,
        const unsigned short* __restrict__ WcatT, int m0, int j, int kt,
        unsigned short* As, unsigned short* Bs, int wid, int lane) {
    int ksel = kt * 32;
    const unsigned short* srcA = (ksel < 128)
        ? xbf + (size_t)m0 * NF + ksel
        : mean1 + (size_t)m0 * NF + (ksel - 128);
#pragma unroll
    for (int ci = 0; ci < 2; ++ci) {
        int cb = ci * 256 + wid * 64;
        int chunk = cb + lane;
        int n = chunk >> 2, kc = chunk & 3;
        lds_dma16(srcA + (size_t)n * NF + kc * 8, &As[cb * 8]);
    }
    const unsigned short* srcB = WcatT + (size_t)(j * 128) * 256 + ksel;
#pragma unroll
    for (int ci = 0; ci < 2; ++ci) {
        int cb = ci * 256 + wid * 64;
        int chunk = cb + lane;
        int n = chunk >> 2, kc = chunk & 3;
        lds_dma16(srcB + (size_t)n * 256 + kc * 8, &Bs[cb * 8]);
    }
}

// ---------------- fused GEMM: depth-2 prefetch w/ raw barriers ---------------
__global__ __launch_bounds__(256, 2) void fused_gemm_kernel(
        const unsigned short* __restrict__ xbf, const unsigned short* __restrict__ mean1,
        const unsigned short* __restrict__ WcatT, const float* __restrict__ b1e,
        const unsigned short* __restrict__ W2catT,
        float* __restrict__ pp0, float* __restrict__ pp1) {
    __shared__ __align__(16) unsigned short As[3][128 * 32];
    __shared__ __align__(16) unsigned short Bs[3][128 * 32];
    __shared__ __align__(16) unsigned short Ht[128 * 128];   // XOR-swizzled

    int m0 = blockIdx.x * 128;
    int jb = blockIdx.y * 6;
    float* pout = blockIdx.y ? pp1 : pp0;
    int tid = threadIdx.x;
    int lane = tid & 63, wid = tid >> 6;
    int wm = wid >> 1, wn = wid & 1;
    int quad = lane >> 4, l15 = lane & 15;

    f32x4 pacc[4][4] = {};

    stage_chunk(xbf, mean1, WcatT, m0, jb, 0, As[0], Bs[0], wid, lane);
    stage_chunk(xbf, mean1, WcatT, m0, jb, 1, As[1], Bs[1], wid, lane);

#pragma unroll
    for (int jj = 0; jj < 6; ++jj) {
        int j = jb + jj;
        f32x4 hacc[4][4] = {};
#pragma unroll
        for (int kt = 0; kt < 8; ++kt) {
            const int g = jj * 8 + kt;
            if (g == 47) wait_vm0(); else wait_vm4();
            raw_barrier();
            if (g + 2 < 48) {
                int g2 = g + 2;
                stage_chunk(xbf, mean1, WcatT, m0, jb + (g2 >> 3), g2 & 7,
                            As[g2 % 3], Bs[g2 % 3], wid, lane);
            }
            const unsigned short* Asb = As[g % 3];
            const unsigned short* Bsb = Bs[g % 3];
            bf16x8 a[4], b[4];
#pragma unroll
            for (int mi = 0; mi < 4; ++mi)
                a[mi] = *(const bf16x8*)(&Asb[(wm * 64 + mi * 16 + l15) * 32 + quad * 8]);
#pragma unroll
            for (int ni = 0; ni < 4; ++ni)
                b[ni] = *(const bf16x8*)(&Bsb[(wn * 64 + ni * 16 + l15) * 32 + quad * 8]);
#pragma unroll
            for (int mi = 0; mi < 4; ++mi)
#pragma unroll
                for (int ni = 0; ni < 4; ++ni)
                    hacc[mi][ni] = __builtin_amdgcn_mfma_f32_16x16x32_bf16(b[ni], a[mi], hacc[mi][ni], 0, 0, 0);
        }
#pragma unroll
        for (int ni = 0; ni < 4; ++ni) {
            int n0 = wn * 64 + ni * 16 + quad * 4;
            float4 bv = *(const float4*)(b1e + j * 128 + n0);
#pragma unroll
            for (int mi = 0; mi < 4; ++mi) {
                int m = wm * 64 + mi * 16 + l15;
                int gsw = ((n0 >> 3) ^ (m & 15));
                ushort4 o;
                o.x = f2bf(fmaxf(hacc[mi][ni][0] + bv.x, 0.f));
                o.y = f2bf(fmaxf(hacc[mi][ni][1] + bv.y, 0.f));
                o.z = f2bf(fmaxf(hacc[mi][ni][2] + bv.z, 0.f));
                o.w = f2bf(fmaxf(hacc[mi][ni][3] + bv.w, 0.f));
                *(ushort4*)(&Ht[m * 128 + gsw * 8 + (n0 & 7)]) = o;
            }
        }
        wait_lgkm0();
        raw_barrier();
#pragma unroll
        for (int kk2 = 0; kk2 < 128; kk2 += 32) {
            bf16x8 a2[4], b2[4];
#pragma unroll
            for (int mi = 0; mi < 4; ++mi) {
                int m = wm * 64 + mi * 16 + l15;
                int gr = (kk2 >> 3) + quad;
                int gsw = gr ^ (m & 15);
                a2[mi] = *(const bf16x8*)(&Ht[m * 128 + gsw * 8]);
            }
#pragma unroll
            for (int ni = 0; ni < 4; ++ni)
                b2[ni] = *(const bf16x8*)(W2catT + (size_t)(wn * 64 + ni * 16 + l15) * NHIDP
                                          + j * 128 + kk2 + quad * 8);
#pragma unroll
            for (int mi = 0; mi < 4; ++mi)
#pragma unroll
                for (int ni = 0; ni < 4; ++ni)
                    pacc[mi][ni] = __builtin_amdgcn_mfma_f32_16x16x32_bf16(b2[ni], a2[mi], pacc[mi][ni], 0, 0, 0);
        }
    }

#pragma unroll
    for (int mi = 0; mi < 4; ++mi) {
        int gr = m0 + wm * 64 + mi * 16 + l15;
        if (gr < RES0) {
#pragma unroll
            for (int ni = 0; ni < 4; ++ni) {
                int gc0 = wn * 64 + ni * 16 + quad * 4;
                *(float4*)(&pout[(size_t)gr * 128 + gc0]) = *(float4*)(&pacc[mi][ni]);
            }
        }
    }
}

// ---------------- padd: pnbf = bf16(pp0+pp1)[:,0:64]; root64 for rows<RES1 ---
__global__ __launch_bounds__(256) void padd_kernel(
        const float* __restrict__ pp0, const float* __restrict__ pp1,
        unsigned short* __restrict__ pnbf, float* __restrict__ root64) {
    int i = blockIdx.x * 256 + threadIdx.x;     // over RES0*8
    if (i >= RES0 * 8) return;
    int row = i >> 3, c8 = i & 7;
    size_t b = (size_t)row * 128 + c8 * 8;
    f32x4 s0 = *(const f32x4*)(pp0 + b)     + *(const f32x4*)(pp1 + b);
    f32x4 s1 = *(const f32x4*)(pp0 + b + 4) + *(const f32x4*)(pp1 + b + 4);
    u16x8 o;
    o[0] = f2bf(s0[0]); o[1] = f2bf(s0[1]); o[2] = f2bf(s0[2]); o[3] = f2bf(s0[3]);
    o[4] = f2bf(s1[0]); o[5] = f2bf(s1[1]); o[6] = f2bf(s1[2]); o[7] = f2bf(s1[3]);
    *(u16x8*)(pnbf + (size_t)row * 64 + c8 * 8) = o;
    if (row < RES1) {
        size_t rb = (size_t)row * 128 + 64 + c8 * 8;
        f32x4 r0 = *(const f32x4*)(pp0 + rb)     + *(const f32x4*)(pp1 + rb);
        f32x4 r1 = *(const f32x4*)(pp0 + rb + 4) + *(const f32x4*)(pp1 + rb + 4);
        *(f32x4*)(root64 + (size_t)row * 64 + c8 * 8)     = r0;
        *(f32x4*)(root64 + (size_t)row * 64 + c8 * 8 + 4) = r1;
    }
}

// ---------------- final: bf16 gathers, 8 edges/instr, wave/row ---------------
__global__ __launch_bounds__(256) void final_csr_kernel(
        const unsigned short* __restrict__ pnbf, const float* __restrict__ root64,
        const int* __restrict__ csr, const u32* __restrict__ off,
        const u32* __restrict__ cnt, const float* __restrict__ b2,
        float* __restrict__ out) {
    int row = blockIdx.x * 4 + (threadIdx.x >> 6);
    int lane = threadIdx.x & 63;
    if (row >= RES1) return;
    int es = lane >> 3, c8 = lane & 7;          // edge slot (0..7), 16B chunk
    u32 base = off[row], deg = cnt[row];
    float acc[8] = {};
    u32 e = 0;
    for (; e + 8 <= deg; e += 8) {
        int s = csr[base + e + es];
        u16x8 v = *(const u16x8*)(pnbf + (size_t)s * 64 + c8 * 8);
#pragma unroll
        for (int i = 0; i < 8; ++i) acc[i] += bf2f(v[i]);
    }
    if (e < deg) {
        bool valid = (e + es) < deg;
        int s = csr[base + (valid ? e + es : e)];
        u16x8 v = *(const u16x8*)(pnbf + (size_t)s * 64 + c8 * 8);
        if (valid) {
#pragma unroll
            for (int i = 0; i < 8; ++i) acc[i] += bf2f(v[i]);
        }
    }
    // reduce across the 8 edge slots (lane bits 3,4,5)
#pragma unroll
    for (int i = 0; i < 8; ++i) {
        acc[i] += __shfl_xor(acc[i], 32, 64);
        acc[i] += __shfl_xor(acc[i], 16, 64);
        acc[i] += __shfl_xor(acc[i], 8, 64);
    }
    float inv = 1.0f / fmaxf((float)deg, 1.0f);
    float v[8];
    const float* rp = root64 + (size_t)row * 64 + c8 * 8;
#pragma unroll
    for (int i = 0; i < 8; ++i) v[i] = rp[i] + acc[i] * inv + b2[c8 * 8 + i];
    float m = v[0];
#pragma unroll
    for (int i = 1; i < 8; ++i) m = fmaxf(m, v[i]);
    // values uniform across es-groups; reduce over c8 (lane bits 0,1,2)
    m = fmaxf(m, __shfl_xor(m, 1, 64));
    m = fmaxf(m, __shfl_xor(m, 2, 64));
    m = fmaxf(m, __shfl_xor(m, 4, 64));
    float s = 0.f;
#pragma unroll
    for (int i = 0; i < 8; ++i) s += expf(v[i] - m);
    s += __shfl_xor(s, 1, 64);
    s += __shfl_xor(s, 2, 64);
    s += __shfl_xor(s, 4, 64);
    if (es == 0) {
        float lg = logf(s);
        f32x4 o0, o1;
#pragma unroll
        for (int i = 0; i < 4; ++i) { o0[i] = v[i] - m - lg; o1[i] = v[i + 4] - m - lg; }
        *(f32x4*)(&out[(size_t)row * 64 + c8 * 8])     = o0;
        *(f32x4*)(&out[(size_t)row * 64 + c8 * 8 + 4]) = o1;
    }
}

extern "C" void kernel_launch(void* const* d_in, const int* in_sizes, int n_in,
                              void* d_out, int out_size, void* d_ws, size_t ws_size,
                              hipStream_t stream) {
    const float* x   = (const float*)d_in[0];
    const float* W1r = (const float*)d_in[1];
    const float* W1n = (const float*)d_in[2];
    const float* b1  = (const float*)d_in[3];
    const float* W2r = (const float*)d_in[4];
    const float* W2n = (const float*)d_in[5];
    const float* b2  = (const float*)d_in[6];
    const int* es0 = (const int*)d_in[7];
    const int* et0 = (const int*)d_in[8];
    const int* es1 = (const int*)d_in[9];
    const int* et1 = (const int*)d_in[10];
    float* out = (float*)d_out;

    char* ws = (char*)d_ws;
    // --- region 0 [0, 25.6 MB): pp1 aliases CSR-phase temporaries (all dead
    //     before fused_gemm writes pp1) ---
    const size_t PPBYTES = (size_t)RES0 * 128 * 4;   // 25,600,000
    float* pp1 = (float*)ws;
    size_t o0 = 0;
    auto alloc0 = [&](size_t bytes) {
        void* ptr = ws + o0;
        o0 = (o0 + bytes + 255) & ~(size_t)255;
        return ptr;
    };
    u64* bkt1  = (u64*)alloc0((size_t)E0N * 8);        // 12.8 MB
    u64* bkt2  = (u64*)alloc0((size_t)E1N * 8);        //  4.0 MB
    int* csr1  = (int*)alloc0((size_t)E0N * 4);        //  6.4 MB
    u32* H1    = (u32*)alloc0((size_t)NCH0 * NB0 * 4);
    u32* base1 = (u32*)alloc0((size_t)NCH0 * NB0 * 4);
    u32* H2    = (u32*)alloc0((size_t)NCH1 * NB1 * 4);
    u32* base2 = (u32*)alloc0((size_t)NCH1 * NB1 * 4);
    u32* Bsum1 = (u32*)alloc0((size_t)NB0 * 4);
    u32* Bsum2 = (u32*)alloc0((size_t)NB1 * 4);
    u32* boff1 = (u32*)alloc0((size_t)NB0 * 4);
    u32* boff2 = (u32*)alloc0((size_t)NB1 * 4);
    u32* off1  = (u32*)alloc0((size_t)RES0 * 4);
    u32* cnt1  = (u32*)alloc0((size_t)RES0 * 4);
    // (o0 ≈ 24.3 MB < 25.6 MB — fits under pp1)

    // --- live region, starts after pp1 ---
    size_t off_ = PPBYTES;
    auto alloc = [&](size_t bytes) {
        void* ptr = ws + off_;
        off_ = (off_ + bytes + 255) & ~(size_t)255;
        return ptr;
    };
    int* csr2  = (int*)alloc((size_t)E1N * 4);
    u32* off2  = (u32*)alloc((size_t)RES1 * 4);
    u32* cnt2  = (u32*)alloc((size_t)RES1 * 4);
    unsigned short* xbf    = (unsigned short*)alloc((size_t)NSRC * NF * 2);
    unsigned short* mean1  = (unsigned short*)alloc((size_t)(RES0 + 128) * NF * 2);
    unsigned short* WcatT  = (unsigned short*)alloc((size_t)NHIDP * 256 * 2);
    unsigned short* W2catT = (unsigned short*)alloc((size_t)128 * NHIDP * 2);
    float*          b1e    = (float*)alloc((size_t)NHIDP * 4);
    float*          pp0    = (float*)alloc(PPBYTES);
    unsigned short* pnbf   = (unsigned short*)alloc((size_t)RES0 * 64 * 2);
    float*          root64 = (float*)alloc((size_t)RES1 * 64 * 4);

    setup_kernel<<<PREP_BLOCKS + COPYX_BLOCKS, 256, 0, stream>>>(
        x, xbf, W1r, W1n, b1, W2r, W2n, WcatT, W2catT, b1e);

    p1a_both_kernel<<<NCH0 + NCH1, 256, 0, stream>>>(et0, et1, H1, H2);
    bscan_both_kernel<<<NB0 + NB1, 512, 0, stream>>>(H1, base1, Bsum1, H2, base2, Bsum2);
    boff_kernel<<<2, 256, 0, stream>>>(Bsum1, boff1, NB0, Bsum2, boff2, NB1);
    p1b_both_kernel<<<NCH0 + NCH1, 256, 0, stream>>>(
        es0, et0, base1, boff1, bkt1, es1, et1, base2, boff2, bkt2);
    p2_both_kernel<<<NB0 + NB1, 1024, 0, stream>>>(
        bkt1, boff1, csr1, off1, cnt1, bkt2, boff2, csr2, off2, cnt2);

    agg1_csr_kernel<<<(RES0 + 3) / 4, 256, 0, stream>>>(
        xbf, csr1, off1, cnt1, mean1);

    fused_gemm_kernel<<<dim3((RES0 + 127) / 128, 2), 256, 0, stream>>>(
        xbf, mean1, WcatT, b1e, W2catT, pp0, pp1);

    padd_kernel<<<(RES0 * 8 + 255) / 256, 256, 0, stream>>>(pp0, pp1, pnbf, root64);

    final_csr_kernel<<<(RES1 + 3) / 4, 256, 0, stream>>>(
        pnbf, root64, csr2, off2, cnt2, b2, out);
}